// Round 5
// baseline (2075.221 us; speedup 1.0000x reference)
//
#include <hip/hip_runtime.h>
#include <math.h>

#define BATCH 32
#define P_TOTAL 8732

// ---------------------------------------------------------------------------
// SSD DetectionOutput, R5.
// R4 crashed: workspace ~384MB exceeded ws_size (R3's 239MB passed). R5 keeps
// R4's conv design (MFMA bf16 3-way split, per-lane direct A from pre-split
// planes, reg-staged double-buffered B-LDS, chunk-major K, split-K partials)
// but time-aliases the workspace down to ~206MB:
//   Region A: planesA(s0,s4,s5) -> planesB(s1,s2,s3)+pauxB -> loc/conf/boxes
//   Region B: pauxA -> scores_t + pc buffers
// Accumulator: two-level f32 (per-9-tap-chunk cb -> ct), R2/R3-class noise.
// Launches: priors | wpk_fill | transposeA | convA<7> | transposeB | convB<10>
//           | epi | decode_softmax | topk_nms | final_topk
// ---------------------------------------------------------------------------

typedef __attribute__((ext_vector_type(8))) short bf16x8;
typedef __attribute__((ext_vector_type(4))) float f32x4;
typedef unsigned int uint;
typedef unsigned short ushort;

struct SQ {
  int C, H, W, HW, M, NL, N, npc, pbase;
  int chunks, parts, mtiles, blkBase, nfw, epiBase, c8shift, fillBase, biasBase, tsBase, gx, nbi;
  uint pmag, hwmag, wmag, nmag, tbmag, txmag;
  long planeOffE, MC, wpkOffB, pauxOffF, biasOffF;
};
struct Tab { SQ q[6]; };
struct WPtrs { const float* lw[6]; const float* lb[6]; const float* cw[6]; const float* cb[6]; };
struct FP3 { const float* f0; const float* f1; const float* f2; };

__device__ __forceinline__ ushort f2bf(float f) {
  uint u = __float_as_uint(f);
  return (ushort)((u + 0x7FFFu + ((u >> 16) & 1u)) >> 16);
}
__device__ __forceinline__ float bf2f(ushort b) { return __uint_as_float(((uint)b) << 16); }

// ---------------- priors (verified R2/R3) ----------------
__global__ void make_priors(float* __restrict__ priors) {
  int p = blockIdx.x * 256 + threadIdx.x;
  if (p >= P_TOTAL) return;
  const int pb1 = 5776, pb2 = 7942, pb3 = 8542, pb4 = 8692, pb5 = 8728;
  int base, fw, npc;
  double m, M, st;
  if (p < pb1)      { base = 0;   fw = 38; npc = 4; m = 30.;  M = 60.;  st = 8.;   }
  else if (p < pb2) { base = pb1; fw = 19; npc = 6; m = 60.;  M = 111.; st = 16.;  }
  else if (p < pb3) { base = pb2; fw = 10; npc = 6; m = 111.; M = 162.; st = 32.;  }
  else if (p < pb4) { base = pb3; fw = 5;  npc = 6; m = 162.; M = 213.; st = 64.;  }
  else if (p < pb5) { base = pb4; fw = 3;  npc = 4; m = 213.; M = 264.; st = 100.; }
  else              { base = pb5; fw = 1;  npc = 4; m = 264.; M = 315.; st = 300.; }
  int lp = p - base;
  int cell = lp / npc, j = lp - cell * npc;
  int y = cell / fw, x = cell - y * fw;
  double w_, h_;
  if (j == 0)      { w_ = m; h_ = m; }
  else if (j == 1) { double ss = sqrt(m * M); w_ = ss; h_ = ss; }
  else {
    int q = j - 2;
    double r = sqrt((q < 2) ? 2.0 : 3.0);
    if ((q & 1) == 0) { w_ = m * r; h_ = m / r; }
    else              { w_ = m / r; h_ = m * r; }
  }
  float wf = (float)w_ / 300.0f;
  float hf = (float)h_ / 300.0f;
  float cx = (float)(((double)x + 0.5) * st / 300.0);
  float cy = (float)(((double)y + 0.5) * st / 300.0);
  float4 pr;
  pr.x = cx - wf * 0.5f; pr.y = cy - hf * 0.5f;
  pr.z = cx + wf * 0.5f; pr.w = cy + hf * 0.5f;
  ((float4*)priors)[p] = pr;
}

// ---------------- NCHW f32 -> 3 bf16 NHWC planes (3 scales per launch) -----
__global__ __launch_bounds__(256) void transpose_split(FP3 fp, SQ qa, SQ qb, SQ qc,
                                                       char* __restrict__ wsb) {
  __shared__ float tile[32][33];
  int bid = blockIdx.x;
  int sel = (bid >= qc.tsBase) ? 2 : (bid >= qb.tsBase) ? 1 : 0;
  SQ q = (sel == 2) ? qc : (sel == 1) ? qb : qa;
  const float* fsrc = (sel == 2) ? fp.f2 : (sel == 1) ? fp.f1 : fp.f0;
  int local = bid - q.tsBase;
  int b = __umulhi((uint)local, q.tbmag);
  int r = local - b * q.nbi;
  int cb_, hwb;
  if (q.gx == 1) { cb_ = r; hwb = 0; }
  else { cb_ = __umulhi((uint)r, q.txmag); hwb = r - cb_ * q.gx; }
  int hw0 = hwb * 32, c0 = cb_ * 32;
  int tx = threadIdx.x & 31, ty = threadIdx.x >> 5;
  const float* ip = fsrc + (size_t)b * q.C * q.HW;
#pragma unroll
  for (int r2 = 0; r2 < 4; ++r2) {
    int c = c0 + ty + 8 * r2;
    int hw = hw0 + tx;
    tile[ty + 8 * r2][tx] = (hw < q.HW) ? ip[(size_t)c * q.HW + hw] : 0.f;
  }
  __syncthreads();
  ushort* p0 = (ushort*)wsb + q.planeOffE;
  long MC = q.MC;
#pragma unroll
  for (int r2 = 0; r2 < 4; ++r2) {
    int hw = hw0 + ty + 8 * r2;
    int c = c0 + tx;
    if (hw < q.HW) {
      float a = tile[tx][ty + 8 * r2];
      ushort h0 = f2bf(a); float t = a - bf2f(h0);
      ushort h1 = f2bf(t); ushort h2 = f2bf(t - bf2f(h1));
      long o = ((long)b * q.HW + hw) * q.C + c;
      p0[o] = h0; p0[o + MC] = h1; p0[o + 2 * MC] = h2;
    }
  }
}

// ---------------- weight pack (chunk-major kb) + bias, pads zeroed ---------
__global__ __launch_bounds__(256) void wpk_fill(WPtrs wp, Tab tb, char* __restrict__ wsb,
                                                int fillTotal, int total) {
  int e = blockIdx.x * 256 + threadIdx.x;
  if (e >= total) return;
  if (e < fillTotal) {
    int s = 0;
#pragma unroll
    for (int i = 1; i < 6; ++i) if (e >= tb.q[i].fillBase) s = i;
    SQ q = tb.q[s];
    int le = e - q.fillBase;
    int C8 = q.C >> 3;
    int n = le >> q.c8shift;
    int co = (le & (C8 - 1)) << 3;
    int f = n >> 4, ln = n & 15, g = (co & 31) >> 3;
    int NF = q.nfw >> 4;
    char* wb = wsb + q.wpkOffB;
    bool realn = n < q.N;
    const float* src = realn ? ((n < q.NL) ? wp.lw[s] + ((size_t)n * q.C + co) * 9
                                           : wp.cw[s] + ((size_t)(n - q.NL) * q.C + co) * 9)
                             : (const float*)0;
#pragma unroll
    for (int tap = 0; tap < 9; ++tap) {
      int kb = (co >> 5) * 9 + tap;
      ushort h0[8], h1[8], h2[8];
#pragma unroll
      for (int i = 0; i < 8; ++i) {
        float a = realn ? src[i * 9 + tap] : 0.f;
        ushort a0 = f2bf(a); float t = a - bf2f(a0);
        ushort a1 = f2bf(t); ushort a2 = f2bf(t - bf2f(a1));
        h0[i] = a0; h1[i] = a1; h2[i] = a2;
      }
      char* d = wb + (size_t)kb * (NF * 3072) + f * 3072 + (g * 16 + ln) * 16;
      *(uint4*)(d)        = *(uint4*)h0;
      *(uint4*)(d + 1024) = *(uint4*)h1;
      *(uint4*)(d + 2048) = *(uint4*)h2;
    }
  } else {
    int e2 = e - fillTotal;
    int s = 0;
#pragma unroll
    for (int i = 1; i < 6; ++i) if (e2 >= tb.q[i].biasBase) s = i;
    SQ q = tb.q[s];
    int ln = e2 - q.biasBase;
    float v = 0.f;
    if (ln < q.N) v = (ln < q.NL) ? wp.lb[s][ln] : wp.cb[s][ln - q.NL];
    ((float*)wsb + q.biasOffF)[ln] = v;
  }
}

// ---------------- MFMA conv ----------------
// A-frag: lane l holds A[m0+32wv+16rf+(l&15)][k: 8*(l>>4)+i] direct from planes
// B-frag: packed wpk, lane*16 within f*3072 (+1024/+2048 for lo planes)
// C/D:    col = lane&15, row = (lane>>4)*4 + reg
template<int NF>
__global__ __launch_bounds__(256, 2) void conv_mfma(char* __restrict__ wsb,
                                                    SQ q0, SQ q1, SQ q2) {
  __shared__ __attribute__((aligned(16))) char smB[2 * NF * 3072];
  const int bid = blockIdx.x;
  SQ q = (bid >= q2.blkBase) ? q2 : (bid >= q1.blkBase) ? q1 : q0;
  int lb = bid - q.blkBase;
  int mt, part;
  if (q.parts == 1) { mt = lb; part = 0; }
  else { mt = __umulhi((uint)lb, q.pmag); part = lb - mt * q.parts; }
  const int m0 = mt << 7;
  int cbeg, cend;
  if (q.parts == 1) { cbeg = 0; cend = q.chunks; }
  else {
    cbeg = __umulhi((uint)(part * q.chunks), q.pmag);
    cend = __umulhi((uint)((part + 1) * q.chunks), q.pmag);
  }
  const int tid = threadIdx.x, lane = tid & 63, wv = tid >> 6;
  const int colf = lane & 15, koct = lane >> 4;
  const ushort* plane0 = (const ushort*)wsb + q.planeOffE;
  const long MC = q.MC;

  int yv[2], xv[2], mvalid[2];
  long pixoff[2];
#pragma unroll
  for (int rf = 0; rf < 2; ++rf) {
    int m = m0 + 32 * wv + 16 * rf + colf;
    int valid = (m < q.M);
    int mc = valid ? m : 0;
    int b, rem;
    if (q.HW == 1) { b = mc; rem = 0; }
    else { b = __umulhi((uint)mc, q.hwmag); rem = mc - b * q.HW; }
    int y, x;
    if (q.W == 1) { y = rem; x = 0; }
    else { y = __umulhi((uint)rem, q.wmag); x = rem - y * q.W; }
    yv[rf] = y; xv[rf] = x; mvalid[rf] = valid;
    pixoff[rf] = ((long)(b * q.H + y) * q.W + x) * q.C + koct * 8;
  }

  f32x4 cb[2][NF], ct[2][NF];
#pragma unroll
  for (int rf = 0; rf < 2; ++rf)
#pragma unroll
    for (int f = 0; f < NF; ++f) { cb[rf][f] = 0.f; ct[rf][f] = 0.f; }

  const int SEG = NF * 192;
  constexpr int NSTG = (NF * 192 + 255) / 256;
  uint4 stg[NSTG];
  const char* wpkb = wsb + q.wpkOffB;
  const int kbeg = cbeg * 9, kend = cend * 9;
  {
    const uint4* s4 = (const uint4*)(wpkb + (size_t)kbeg * (NF * 3072));
#pragma unroll
    for (int j = 0; j < NSTG; ++j) { int c = tid + j * 256; if (c < SEG) stg[j] = s4[c]; }
  }
  int cur = 0, chunk = cbeg, tap = 0;
  for (int kb = kbeg; kb < kend; ++kb) {
    {
      uint4* d = (uint4*)(smB + cur * (NF * 3072));
#pragma unroll
      for (int j = 0; j < NSTG; ++j) { int c = tid + j * 256; if (c < SEG) d[c] = stg[j]; }
    }
    __syncthreads();
    if (kb + 1 < kend) {
      const uint4* s4 = (const uint4*)(wpkb + (size_t)(kb + 1) * (NF * 3072));
#pragma unroll
      for (int j = 0; j < NSTG; ++j) { int c = tid + j * 256; if (c < SEG) stg[j] = s4[c]; }
    }
    // A fragments (direct global, masked)
    int t3 = (tap * 43) >> 7;
    int dy = t3 - 1, dx = tap - t3 * 3 - 1;
    long soff = (long)(dy * q.W + dx) * q.C + (chunk << 5);
    bf16x8 a0[2], a1[2], a2[2];
#pragma unroll
    for (int rf = 0; rf < 2; ++rf) {
      int ok = mvalid[rf] & ((uint)(yv[rf] + dy) < (uint)q.H) & ((uint)(xv[rf] + dx) < (uint)q.W);
      const ushort* ap = plane0 + (pixoff[rf] + soff);
      uint4 v0 = *(const uint4*)(ap);
      uint4 v1 = *(const uint4*)(ap + MC);
      uint4 v2 = *(const uint4*)(ap + 2 * MC);
      if (!ok) { v0.x = v0.y = v0.z = v0.w = 0u; v1 = v0; v2 = v0; }
      a0[rf] = *(bf16x8*)&v0; a1[rf] = *(bf16x8*)&v1; a2[rf] = *(bf16x8*)&v2;
    }
    const char* bb = smB + cur * (NF * 3072) + lane * 16;
#pragma unroll
    for (int f = 0; f < NF; ++f) {
      bf16x8 b0 = *(const bf16x8*)(bb + f * 3072);
      bf16x8 b1 = *(const bf16x8*)(bb + f * 3072 + 1024);
      bf16x8 b2 = *(const bf16x8*)(bb + f * 3072 + 2048);
#pragma unroll
      for (int rf = 0; rf < 2; ++rf) {
        cb[rf][f] = __builtin_amdgcn_mfma_f32_16x16x32_bf16(a0[rf], b0, cb[rf][f], 0, 0, 0);
        cb[rf][f] = __builtin_amdgcn_mfma_f32_16x16x32_bf16(a1[rf], b0, cb[rf][f], 0, 0, 0);
        cb[rf][f] = __builtin_amdgcn_mfma_f32_16x16x32_bf16(a0[rf], b1, cb[rf][f], 0, 0, 0);
        cb[rf][f] = __builtin_amdgcn_mfma_f32_16x16x32_bf16(a1[rf], b1, cb[rf][f], 0, 0, 0);
        cb[rf][f] = __builtin_amdgcn_mfma_f32_16x16x32_bf16(a2[rf], b0, cb[rf][f], 0, 0, 0);
        cb[rf][f] = __builtin_amdgcn_mfma_f32_16x16x32_bf16(a0[rf], b2, cb[rf][f], 0, 0, 0);
      }
    }
    if (tap == 8) {  // chunk boundary: promote f32 block into ct
#pragma unroll
      for (int rf = 0; rf < 2; ++rf)
#pragma unroll
        for (int f = 0; f < NF; ++f) { ct[rf][f] += cb[rf][f]; cb[rf][f] = 0.f; }
    }
    cur ^= 1;
    if (++tap == 9) { tap = 0; ++chunk; }
  }

  float* paux = (float*)wsb + q.pauxOffF + (long)part * q.M * q.nfw;
#pragma unroll
  for (int rf = 0; rf < 2; ++rf)
#pragma unroll
    for (int f = 0; f < NF; ++f) {
      int n = f * 16 + colf;
      int mr = m0 + 32 * wv + 16 * rf + 4 * koct;
#pragma unroll
      for (int r = 0; r < 4; ++r) {
        int m = mr + r;
        if (m < q.M) paux[(long)m * q.nfw + n] = ct[rf][f][r];
      }
    }
}

// ---------------- epilogue: sum parts + bias + scatter to loc/conf --------
__global__ __launch_bounds__(256) void epi(const char* __restrict__ wsb, Tab tb,
                                           float* __restrict__ locbuf,
                                           float* __restrict__ confbuf) {
  int bid = blockIdx.x;
  int s = 0;
#pragma unroll
  for (int i = 1; i < 6; ++i) if (bid >= tb.q[i].epiBase) s = i;
  SQ q = tb.q[s];
  int e = (bid - q.epiBase) * 256 + threadIdx.x;
  if (e >= q.M * q.N) return;
  int m = __umulhi((uint)e, q.nmag);
  int n = e - m * q.N;
  const float* pa = (const float*)wsb + q.pauxOffF + (long)m * q.nfw + n;
  float v = ((const float*)wsb + q.biasOffF)[n];
  long pstride = (long)q.M * q.nfw;
  for (int p = 0; p < q.parts; ++p) v += pa[p * pstride];
  int b, rem;
  if (q.HW == 1) { b = m; rem = 0; }
  else { b = __umulhi((uint)m, q.hwmag); rem = m - b * q.HW; }
  int pidx0 = q.pbase + rem * q.npc;
  if (n < q.NL) {
    locbuf[((long)b * P_TOTAL + pidx0 + (n >> 2)) * 4 + (n & 3)] = v;
  } else {
    int cn = n - q.NL;
    int pr = __umulhi((uint)cn, 204522253u);
    int cl = cn - pr * 21;
    confbuf[((long)b * P_TOTAL + pidx0 + pr) * 21 + cl] = v;
  }
}

// ---------------- softmax + box decode (verified R3) ----------------
__global__ __launch_bounds__(256) void decode_softmax(const float* __restrict__ locbuf,
                                                      const float* __restrict__ confbuf,
                                                      const float* __restrict__ priors,
                                                      float* __restrict__ boxes,
                                                      float* __restrict__ scores_t) {
  __shared__ float sc[20 * 256];
  int b = blockIdx.y;
  int p0 = blockIdx.x * 256;
  int tid = threadIdx.x;
  int p = p0 + tid;
  if (p < P_TOTAL) {
    long t = (long)b * P_TOTAL + p;
    float4 pri = ((const float4*)priors)[p];
    float4 lo = ((const float4*)locbuf)[t];
    float pw = pri.z - pri.x, ph = pri.w - pri.y;
    float pcx = (pri.x + pri.z) * 0.5f, pcy = (pri.y + pri.w) * 0.5f;
    float cx = pcx + 0.1f * lo.x * pw;
    float cy = pcy + 0.1f * lo.y * ph;
    float w = pw * expf(0.2f * lo.z);
    float h = ph * expf(0.2f * lo.w);
    float4 bx;
    bx.x = cx - w * 0.5f; bx.y = cy - h * 0.5f;
    bx.z = cx + w * 0.5f; bx.w = cy + h * 0.5f;
    ((float4*)boxes)[t] = bx;
    const float* cp = confbuf + t * 21;
    float l[21];
#pragma unroll
    for (int c = 0; c < 21; ++c) l[c] = cp[c];
    float mx = l[0];
#pragma unroll
    for (int c = 1; c < 21; ++c) mx = fmaxf(mx, l[c]);
    float e[21];
    float sum = 0.f;
#pragma unroll
    for (int c = 0; c < 21; ++c) { e[c] = expf(l[c] - mx); sum += e[c]; }
#pragma unroll
    for (int c = 1; c < 21; ++c) sc[(c - 1) * 256 + tid] = e[c] / sum;
  } else {
#pragma unroll
    for (int c = 0; c < 20; ++c) sc[c * 256 + tid] = 0.f;
  }
  __syncthreads();
  int np = min(256, P_TOTAL - p0);
  if (tid < np) {
    for (int c = 0; c < 20; ++c)
      scores_t[((long)b * 20 + c) * P_TOTAL + p0 + tid] = sc[c * 256 + tid];
  }
}

// ---------------- per-(image,class) top-200 + greedy NMS (verified R2) -----
__global__ __launch_bounds__(256) void topk_nms(const float* __restrict__ scores_t,
                                                const float* __restrict__ boxes,
                                                float* __restrict__ pc_scores,
                                                float* __restrict__ pc_boxes) {
  int bc = blockIdx.x;
  int b = bc / 20;
  int tid = threadIdx.x;
  const float* sp = scores_t + (long)bc * P_TOTAL;

  float vals[35];
#pragma unroll
  for (int u = 0; u < 35; ++u) {
    int idx = u * 256 + tid;
    float v = -1.f;
    if (idx < P_TOTAL) {
      float s = sp[idx];
      v = (s > 0.01f) ? s : 0.f;
    }
    vals[u] = v;
  }

  __shared__ unsigned long long wred[4];
  __shared__ unsigned long long winner;
  __shared__ int sel_idx[200];
  __shared__ float sel_sc[200];
  __shared__ float bX1[200], bY1[200], bX2[200], bY2[200], bAr[200];

  for (int r = 0; r < 200; ++r) {
    float bv = vals[0]; int bu = 0;
#pragma unroll
    for (int u = 1; u < 35; ++u)
      if (vals[u] > bv) { bv = vals[u]; bu = u; }
    int bidx = bu * 256 + tid;
    unsigned long long key = (bv < 0.f) ? 0ull
        : (((unsigned long long)__float_as_uint(bv) << 32) | (unsigned)(0x7FFFFFFF - bidx));
#pragma unroll
    for (int off = 32; off > 0; off >>= 1) {
      unsigned long long o = __shfl_down(key, off);
      if (o > key) key = o;
    }
    if ((tid & 63) == 0) wred[tid >> 6] = key;
    __syncthreads();
    if (tid == 0) {
      unsigned long long k0 = wred[0];
      for (int w = 1; w < 4; ++w) if (wred[w] > k0) k0 = wred[w];
      winner = k0;
      sel_idx[r] = 0x7FFFFFFF - (int)(unsigned)(k0 & 0xFFFFFFFFu);
      sel_sc[r] = __uint_as_float((unsigned)(k0 >> 32));
    }
    __syncthreads();
    int wi = 0x7FFFFFFF - (int)(unsigned)(winner & 0xFFFFFFFFu);
    if ((wi & 255) == tid) {
      int u = wi >> 8;
#pragma unroll
      for (int uu = 0; uu < 35; ++uu) if (uu == u) vals[uu] = -1.f;
    }
    __syncthreads();
  }

  if (tid < 200) {
    int ii = sel_idx[tid];
    float4 bx = ((const float4*)boxes)[(long)b * P_TOTAL + ii];
    bX1[tid] = bx.x; bY1[tid] = bx.y; bX2[tid] = bx.z; bY2[tid] = bx.w;
    bAr[tid] = (bx.z - bx.x) * (bx.w - bx.y);
  }
  __syncthreads();

  if (tid < 64) {
    float mx1[4], my1[4], mx2[4], my2[4], ma[4];
    unsigned km = 0;
#pragma unroll
    for (int s2 = 0; s2 < 4; ++s2) {
      int j = tid + 64 * s2;
      if (j < 200) {
        mx1[s2] = bX1[j]; my1[s2] = bY1[j]; mx2[s2] = bX2[j]; my2[s2] = bY2[j]; ma[s2] = bAr[j];
        if (sel_sc[j] > 0.f) km |= 1u << s2;
      } else {
        mx1[s2] = 0.f; my1[s2] = 0.f; mx2[s2] = 0.f; my2[s2] = 0.f; ma[s2] = 0.f;
      }
    }
    for (int i = 0; i < 200; ++i) {
      int owner = i & 63, slot = i >> 6;
      unsigned kmi = __shfl(km, owner);
      if ((kmi >> slot) & 1) {
        float ix1 = bX1[i], iy1 = bY1[i], ix2 = bX2[i], iy2 = bY2[i], ia = bAr[i];
#pragma unroll
        for (int s2 = 0; s2 < 4; ++s2) {
          int j = tid + 64 * s2;
          if (j < 200 && j > i) {
            float xx1 = fmaxf(ix1, mx1[s2]);
            float yy1 = fmaxf(iy1, my1[s2]);
            float xx2 = fminf(ix2, mx2[s2]);
            float yy2 = fminf(iy2, my2[s2]);
            float inter = fmaxf(xx2 - xx1, 0.f) * fmaxf(yy2 - yy1, 0.f);
            float uni = fmaxf(ia + ma[s2] - inter, 1e-9f);
            if (inter / uni > 0.45f) km &= ~(1u << s2);
          }
        }
      }
    }
#pragma unroll
    for (int s2 = 0; s2 < 4; ++s2) {
      int j = tid + 64 * s2;
      if (j < 200) {
        long o = (long)bc * 200 + j;
        pc_scores[o] = ((km >> s2) & 1) ? sel_sc[j] : 0.f;
        float4 ob; ob.x = mx1[s2]; ob.y = my1[s2]; ob.z = mx2[s2]; ob.w = my2[s2];
        ((float4*)pc_boxes)[o] = ob;
      }
    }
  }
}

// ---------------- final per-image top-200 + emit (verified R2) ------------
__global__ __launch_bounds__(256) void final_topk(const float* __restrict__ pc_scores,
                                                  const float* __restrict__ pc_boxes,
                                                  float* __restrict__ out) {
  int b = blockIdx.x;
  int tid = threadIdx.x;
  const float* fs = pc_scores + (long)b * 4000;
  float vals[16];
#pragma unroll
  for (int u = 0; u < 16; ++u) {
    int idx = u * 256 + tid;
    vals[u] = (idx < 4000) ? fs[idx] : -1.f;
  }
  __shared__ unsigned long long wred[4];
  __shared__ unsigned long long winner;
  __shared__ int kidx[200];
  __shared__ float ksc[200];
  for (int r = 0; r < 200; ++r) {
    float bv = vals[0]; int bu = 0;
#pragma unroll
    for (int u = 1; u < 16; ++u)
      if (vals[u] > bv) { bv = vals[u]; bu = u; }
    int bidx = bu * 256 + tid;
    unsigned long long key = (bv < 0.f) ? 0ull
        : (((unsigned long long)__float_as_uint(bv) << 32) | (unsigned)(0x7FFFFFFF - bidx));
#pragma unroll
    for (int off = 32; off > 0; off >>= 1) {
      unsigned long long o = __shfl_down(key, off);
      if (o > key) key = o;
    }
    if ((tid & 63) == 0) wred[tid >> 6] = key;
    __syncthreads();
    if (tid == 0) {
      unsigned long long k0 = wred[0];
      for (int w = 1; w < 4; ++w) if (wred[w] > k0) k0 = wred[w];
      winner = k0;
      kidx[r] = 0x7FFFFFFF - (int)(unsigned)(k0 & 0xFFFFFFFFu);
      ksc[r] = __uint_as_float((unsigned)(k0 >> 32));
    }
    __syncthreads();
    int wi = 0x7FFFFFFF - (int)(unsigned)(winner & 0xFFFFFFFFu);
    if ((wi & 255) == tid) {
      int u = wi >> 8;
#pragma unroll
      for (int uu = 0; uu < 16; ++uu) if (uu == u) vals[uu] = -1.f;
    }
    __syncthreads();
  }
  if (tid < 200) {
    int j = kidx[tid];
    float sc2 = ksc[tid];
    float4 bx = ((const float4*)pc_boxes)[(long)b * 4000 + j];
    float lab = (sc2 > 0.f) ? (float)(1 + j / 200) : -1.f;
    long o = ((long)b * 200 + tid) * 7;
    out[o + 0] = (float)b;
    out[o + 1] = lab;
    out[o + 2] = sc2;
    out[o + 3] = bx.x; out[o + 4] = bx.y; out[o + 5] = bx.z; out[o + 6] = bx.w;
  }
}

// ---------------------------------------------------------------------------
static inline uint magu(uint d) { return (uint)((0x100000000ull + d - 1) / d); }
static inline size_t al256(size_t v) { return (v + 255) & ~(size_t)255; }

extern "C" void kernel_launch(void* const* d_in, const int* in_sizes, int n_in,
                              void* d_out, int out_size, void* d_ws, size_t ws_size,
                              hipStream_t stream) {
  (void)in_sizes; (void)n_in; (void)out_size; (void)ws_size;
  static const int CH[6]    = {512, 1024, 512, 256, 256, 256};
  static const int FHW[6]   = {38, 19, 10, 5, 3, 1};
  static const int NPC[6]   = {4, 6, 6, 6, 4, 4};
  static const int PARTS[6] = {2, 4, 4, 2, 2, 1};
  static const int GRPA[3] = {0, 4, 5};
  static const int GRPB[3] = {1, 2, 3};
  char* wsb = (char*)d_ws;
  Tab tb;
  WPtrs wp;
  int pb = 0;
  for (int s = 0; s < 6; ++s) {
    SQ& q = tb.q[s];
    q.C = CH[s]; q.H = FHW[s]; q.W = FHW[s]; q.HW = FHW[s] * FHW[s];
    q.M = BATCH * q.HW;
    q.npc = NPC[s]; q.NL = NPC[s] * 4; q.N = NPC[s] * 25;
    q.nfw = ((q.N + 15) >> 4) << 4;   // 112 or 160
    q.pbase = pb; pb += q.HW * q.npc;
    q.chunks = q.C >> 5;
    q.parts = PARTS[s];
    q.mtiles = (q.M + 127) >> 7;
    q.pmag = (q.parts >= 2) ? magu((uint)q.parts) : 0;
    q.hwmag = (q.HW >= 2) ? magu((uint)q.HW) : 0;
    q.wmag = (q.W >= 2) ? magu((uint)q.W) : 0;
    q.nmag = magu((uint)q.N);
    q.MC = (long)q.M * q.C;
    int c8 = q.C >> 3;
    q.c8shift = (c8 == 128) ? 7 : (c8 == 64) ? 6 : 5;
  }
  // ---- static regions: wpk, bias, priors ----
  size_t off = 0;
  for (int s = 0; s < 6; ++s) {
    SQ& q = tb.q[s];
    int NF = q.nfw >> 4;
    q.wpkOffB = (long)off;
    off = al256(off + (size_t)(q.chunks * 9) * NF * 3072);
  }
  for (int s = 0; s < 6; ++s) {
    SQ& q = tb.q[s];
    q.biasOffF = (long)(off >> 2);
    off = al256(off + (size_t)q.nfw * 4);
  }
  size_t priorsOffB = off; off = al256(off + (size_t)P_TOTAL * 16);

  // ---- Region A: planesA | planesB+pauxB | loc/conf/boxes (time-aliased) ----
  size_t Ab = off;
  size_t ca = Ab;
  for (int gi = 0; gi < 3; ++gi) {
    SQ& q = tb.q[GRPA[gi]];
    q.planeOffE = (long)(ca >> 1);
    ca = al256(ca + (size_t)3 * q.MC * 2);
  }
  size_t endPlanesA = ca;
  size_t cb2 = Ab;
  for (int gi = 0; gi < 3; ++gi) {
    SQ& q = tb.q[GRPB[gi]];
    q.planeOffE = (long)(cb2 >> 1);
    cb2 = al256(cb2 + (size_t)3 * q.MC * 2);
  }
  for (int gi = 0; gi < 3; ++gi) {  // pauxB right after planesB
    SQ& q = tb.q[GRPB[gi]];
    q.pauxOffF = (long)(cb2 >> 2);
    cb2 = al256(cb2 + (size_t)q.parts * q.M * q.nfw * 4);
  }
  size_t endB2 = cb2;
  size_t locOffB   = Ab;
  size_t confOffB  = al256(locOffB + (size_t)BATCH * P_TOTAL * 16);
  size_t boxesOffB = al256(confOffB + (size_t)BATCH * P_TOTAL * 21 * 4);
  size_t endLCB    = al256(boxesOffB + (size_t)BATCH * P_TOTAL * 16);
  size_t Aend = endPlanesA;
  if (endB2 > Aend) Aend = endB2;
  if (endLCB > Aend) Aend = endLCB;

  // ---- Region B: pauxA | scores_t+pc (time-aliased) ----
  size_t Bb = al256(Aend);
  size_t cc = Bb;
  for (int gi = 0; gi < 3; ++gi) {
    SQ& q = tb.q[GRPA[gi]];
    q.pauxOffF = (long)(cc >> 2);
    cc = al256(cc + (size_t)q.parts * q.M * q.nfw * 4);
  }
  size_t scTOffB  = Bb;
  size_t pcScOffB = al256(scTOffB + (size_t)BATCH * 20 * P_TOTAL * 4);
  size_t pcBxOffB = al256(pcScOffB + (size_t)BATCH * 20 * 200 * 4);

  // ---- fill/bias/epi/transpose index bases ----
  int fb = 0, bb2 = 0, eb = 0;
  for (int s = 0; s < 6; ++s) {
    SQ& q = tb.q[s];
    q.fillBase = fb; fb += q.nfw * (q.C >> 3);
    q.biasBase = bb2; bb2 += q.nfw;
    q.epiBase = eb; eb += (q.M * q.N + 255) >> 8;
    q.gx = (q.HW + 31) >> 5;
    q.nbi = q.gx * (q.C >> 5);
    q.tbmag = magu((uint)q.nbi);
    q.txmag = (q.gx >= 2) ? magu((uint)q.gx) : 0;
  }
  int fillTotal = fb, wpkTotal = fb + bb2, epiBlocks = eb;

  for (int s = 0; s < 6; ++s) {
    wp.lw[s] = (const float*)d_in[7 + 4 * s];
    wp.lb[s] = (const float*)d_in[8 + 4 * s];
    wp.cw[s] = (const float*)d_in[9 + 4 * s];
    wp.cb[s] = (const float*)d_in[10 + 4 * s];
  }

  float* priors   = (float*)(wsb + priorsOffB);
  float* locbuf   = (float*)(wsb + locOffB);
  float* confbuf  = (float*)(wsb + confOffB);
  float* boxes    = (float*)(wsb + boxesOffB);
  float* scores_t = (float*)(wsb + scTOffB);
  float* pcSc     = (float*)(wsb + pcScOffB);
  float* pcBx     = (float*)(wsb + pcBxOffB);

  make_priors<<<(P_TOTAL + 255) / 256, 256, 0, stream>>>(priors);
  wpk_fill<<<(wpkTotal + 255) / 256, 256, 0, stream>>>(wp, tb, wsb, fillTotal, wpkTotal);

  {  // group A: transpose s0,s4,s5 -> planesA, then conv (NF=7)
    SQ qa = tb.q[0], qb = tb.q[4], qc = tb.q[5];
    qa.tsBase = 0;
    qb.tsBase = qa.nbi * BATCH;
    qc.tsBase = qb.tsBase + qb.nbi * BATCH;
    int tgrid = qc.tsBase + qc.nbi * BATCH;
    FP3 f3; f3.f0 = (const float*)d_in[0]; f3.f1 = (const float*)d_in[4]; f3.f2 = (const float*)d_in[5];
    transpose_split<<<tgrid, 256, 0, stream>>>(f3, qa, qb, qc, wsb);
    qa.blkBase = 0;
    qb.blkBase = qa.mtiles * qa.parts;
    qc.blkBase = qb.blkBase + qb.mtiles * qb.parts;
    int grid = qc.blkBase + qc.mtiles * qc.parts;  // 729
    conv_mfma<7><<<grid, 256, 0, stream>>>(wsb, qa, qb, qc);
  }
  {  // group B: transpose s1,s2,s3 -> planesB (reuses region A), conv (NF=10)
    SQ qa = tb.q[1], qb = tb.q[2], qc = tb.q[3];
    qa.tsBase = 0;
    qb.tsBase = qa.nbi * BATCH;
    qc.tsBase = qb.tsBase + qb.nbi * BATCH;
    int tgrid = qc.tsBase + qc.nbi * BATCH;
    FP3 f3; f3.f0 = (const float*)d_in[1]; f3.f1 = (const float*)d_in[2]; f3.f2 = (const float*)d_in[3];
    transpose_split<<<tgrid, 256, 0, stream>>>(f3, qa, qb, qc, wsb);
    qa.blkBase = 0;
    qb.blkBase = qa.mtiles * qa.parts;
    qc.blkBase = qb.blkBase + qb.mtiles * qb.parts;
    int grid = qc.blkBase + qc.mtiles * qc.parts;  // 478
    conv_mfma<10><<<grid, 256, 0, stream>>>(wsb, qa, qb, qc);
  }

  epi<<<epiBlocks, 256, 0, stream>>>(wsb, tb, locbuf, confbuf);

  decode_softmax<<<dim3(35, BATCH), 256, 0, stream>>>(locbuf, confbuf, priors, boxes, scores_t);

  topk_nms<<<BATCH * 20, 256, 0, stream>>>(scores_t, boxes, pcSc, pcBx);

  final_topk<<<BATCH, 256, 0, stream>>>(pcSc, pcBx, (float*)d_out);
}